// Round 16
// baseline (161.508 us; speedup 1.0000x reference)
//
#include <hip/hip_runtime.h>
#include <stdint.h>

#define RT    2336          // routes
#define RL    1024          // uji routes in LDS per batch (chunks 0..7)
#define NCH   18            // DMA-staged W chunks of 128 routes (0..2303)
#define NRS3  10            // residue slots from chunks 8..17 (+1 tail slot)
#define NSL3  8             // pass slices over uji: RL*4/512 EXACT (no tail)
#define NTH   512
#define NBLK  1024          // one block per (b-pair, k), XCD swizzled
#define BATCH 1024
#define SH1   32.0f         // fixed softmax exponent shift, pass 2 (ratio cancels)
#define SH2   64.0f         // fixed softmax exponent shift, pass 3

typedef float v2f __attribute__((ext_vector_type(2)));

__device__ __forceinline__ float blo(uint32_t v){ union {uint32_t u; float f;} x; x.u = v << 16;        return x.f; }
__device__ __forceinline__ float bhi(uint32_t v){ union {uint32_t u; float f;} x; x.u = v & 0xffff0000u; return x.f; }

// 2x f32 -> packed bf16, one instruction (RNE; R13-verified bit-identical).
__device__ __forceinline__ uint32_t cvtpk_bf16(float a, float b){
  uint32_t r;
  asm("v_cvt_pk_bf16_f32 %0, %1, %2" : "=v"(r) : "v"(a), "v"(b));
  return r;
}

// Packed 2x f32 VOP3P: exact f32 math, half the issue count (R13-verified).
__device__ __forceinline__ v2f pk_fma(v2f a, v2f b, v2f c){
  v2f d; asm("v_pk_fma_f32 %0, %1, %2, %3" : "=v"(d) : "v"(a), "v"(b), "v"(c));
  return d;
}
__device__ __forceinline__ v2f pk_mul(v2f a, v2f b){
  v2f d; asm("v_pk_mul_f32 %0, %1, %2" : "=v"(d) : "v"(a), "v"(b));
  return d;
}
__device__ __forceinline__ v2f pk_add(v2f a, v2f b){
  v2f d; asm("v_pk_add_f32 %0, %1, %2" : "=v"(d) : "v"(a), "v"(b));
  return d;
}

// Quad (4-lane) all-reduce sum via DPP quad_perm (VALU pipe, no LDS).
__device__ __forceinline__ float qsum4(float d){
  d += __int_as_float(__builtin_amdgcn_update_dpp(
         0, __float_as_int(d), 0xB1, 0xF, 0xF, true));
  d += __int_as_float(__builtin_amdgcn_update_dpp(
         0, __float_as_int(d), 0x4E, 0xF, 0xF, true));
  return d;
}

// Dual-batch block merge: batches A,B reduced in one barrier pair.
__device__ __forceinline__ void merge2(float4 aA, float lA, float4 aB, float lB,
                                       int tid, float (*red)[8][4][5],
                                       float (*vbuf)[16],
                                       bool last, float* outp){
  #pragma unroll
  for (int off = 32; off >= 4; off >>= 1){
    aA.x += __shfl_down(aA.x, off); aA.y += __shfl_down(aA.y, off);
    aA.z += __shfl_down(aA.z, off); aA.w += __shfl_down(aA.w, off);
    lA   += __shfl_down(lA,   off);
    aB.x += __shfl_down(aB.x, off); aB.y += __shfl_down(aB.y, off);
    aB.z += __shfl_down(aB.z, off); aB.w += __shfl_down(aB.w, off);
    lB   += __shfl_down(lB,   off);
  }
  const int lane = tid & 63, wid = tid >> 6;
  if (lane < 4){
    red[0][wid][lane][0] = lA;
    red[0][wid][lane][1] = aA.x; red[0][wid][lane][2] = aA.y;
    red[0][wid][lane][3] = aA.z; red[0][wid][lane][4] = aA.w;
    red[1][wid][lane][0] = lB;
    red[1][wid][lane][1] = aB.x; red[1][wid][lane][2] = aB.y;
    red[1][wid][lane][3] = aB.z; red[1][wid][lane][4] = aB.w;
  }
  __syncthreads();
  if (tid < 32){
    const int bt = tid >> 4, t = tid & 15, q = t >> 2, j = t & 3;
    float S = 0.f, partL = 0.f;
    #pragma unroll
    for (int w = 0; w < 8; ++w){
      S     += red[bt][w][q][1 + j];
      partL += red[bt][w][j][0];
    }
    partL += __shfl_xor(partL, 1);
    partL += __shfl_xor(partL, 2);
    float L   = partL * 0.25f;        // 4 qo-threads count each route once
    float inv = 1.f / L;
    float Sn  = S * inv;              // s = acc / L
    float nrm = Sn * Sn;              // squared norm over 16 outputs
    nrm += __shfl_xor(nrm, 1);
    nrm += __shfl_xor(nrm, 2);
    nrm += __shfl_xor(nrm, 4);
    nrm += __shfl_xor(nrm, 8);
    if (last){
      if (t == 0) outp[bt << 1] = nrm / (1.f + nrm);  // ||squash|| = n/(1+n)
    } else {
      float f = sqrtf(nrm) / (1.f + nrm);
      vbuf[bt][t] = Sn * f;
    }
  }
  __syncthreads();
}

// R13 pair structure + DMA-staged W: phase A was the stall (waves idle ~85%,
// ~114 dependent L2 loads/thread at ~200cy, shallow overlap). W now streams
// via global_load_lds double-buffer (issue chunk c+1 after barrier, compute
// chunk c from LDS); u gets a 1-chunk register prefetch. LDS 129.4 KB ->
// 1 block/CU (unchanged empirically for pair config). launch_bounds arg=1 ->
// VGPR cap 256: no spill risk, no occupancy cost (LDS pins 1 block anyway).
__global__ void __launch_bounds__(NTH, 1)
caps_route(const float* __restrict__ U, const float* __restrict__ W,
           float* __restrict__ Out){
  __shared__ uint4 uj4[RL * 4];       // 64 KiB  [route*4+qo] {A01,A23,B01,B23}
  __shared__ float wst[2][8192];      // 2 x 32 KiB W stage (raw f32)
  __shared__ float red[2][8][4][5];   // 1.25 KiB
  __shared__ float vbuf[2][16];

  const int tid  = threadIdx.x;
  const int qo   = tid & 3;           // my o-quad: o = 4*qo .. 4*qo+3
  const int q    = tid >> 2;          // quad id = route index within a chunk
  const int wv   = tid >> 6;          // wave id (wave-uniform)
  const int lane = tid & 63;

  // XCD swizzle (bijective): k=0/1 of one pair adjacent on same XCD.
  const int c8   = blockIdx.x & 7;
  const int jj   = blockIdx.x >> 3;   // 0..127
  const int k    = jj & 1;
  const int pair = (c8 << 6) | (jj >> 1);  // 0..511
  const int bb   = pair << 1;         // b0 = bb, b1 = bb+1

  const float* Ub0 = U + (size_t)bb * (RT * 4);
  const float* Ub1 = Ub0 + (RT * 4);
  const char*  Wb  = (const char*)W + (size_t)k * RT * 256;  // W_k, 256 B/route

  uint2 ura[NRS3 + 1], urb[NRS3 + 1]; // bf16-packed residue (+ tail slot 10)
  float vA0,vA1,vA2,vA3, vB0,vB1,vB2,vB3;

  // Async DMA one 32 KiB W chunk (128 routes) -> wst[buf].
  // LDS dest per call is wave-uniform; HW scatters lane i at +i*16.
  auto dma = [&](int c, int buf){
    const char* g = Wb + ((size_t)c << 15) + (wv << 12) + (lane << 4);
    char* l = (char*)&wst[buf][0] + (wv << 12);
    #pragma unroll
    for (int j = 0; j < 4; ++j)
      __builtin_amdgcn_global_load_lds(
        (const __attribute__((address_space(1))) uint32_t*)(g + (j << 10)),
        (__attribute__((address_space(3))) uint32_t*)(l + (j << 10)),
        16, 0, 0);
  };

  v2f accA01={0.f,0.f}, accA23={0.f,0.f}, accB01={0.f,0.f}, accB23={0.f,0.f};

  // ---------------- Phase A -------------------------------------------------
  dma(0, 0);                          // chunk 0 in flight

  // Tail routes 2304..2335 (quads q<32): direct from global; overlaps DMA 0.
  if (tid < 128){
    int rt = 2304 + q;
    float4 ua = *(const float4*)(Ub0 + (size_t)rt * 4);
    float4 ub = *(const float4*)(Ub1 + (size_t)rt * 4);
    const float* wr = (const float*)(Wb + (size_t)rt * 256) + (qo << 2);
    float4 w0 = *(const float4*)(wr);
    float4 w1 = *(const float4*)(wr + 16);
    float4 w2 = *(const float4*)(wr + 32);
    float4 w3 = *(const float4*)(wr + 48);
    v2f w0l={w0.x,w0.y}, w0h={w0.z,w0.w}, w1l={w1.x,w1.y}, w1h={w1.z,w1.w};
    v2f w2l={w2.x,w2.y}, w2h={w2.z,w2.w}, w3l={w3.x,w3.y}, w3h={w3.z,w3.w};
    v2f sa0={ua.x,ua.x}, sa1={ua.y,ua.y}, sa2={ua.z,ua.z}, sa3={ua.w,ua.w};
    v2f sb0={ub.x,ub.x}, sb1={ub.y,ub.y}, sb2={ub.z,ub.z}, sb3={ub.w,ub.w};
    v2f pa01 = pk_mul(sa0,w0l), pa23 = pk_mul(sa0,w0h);
    pa01 = pk_fma(sa1,w1l,pa01); pa23 = pk_fma(sa1,w1h,pa23);
    pa01 = pk_fma(sa2,w2l,pa01); pa23 = pk_fma(sa2,w2h,pa23);
    pa01 = pk_fma(sa3,w3l,pa01); pa23 = pk_fma(sa3,w3h,pa23);
    v2f pb01 = pk_mul(sb0,w0l), pb23 = pk_mul(sb0,w0h);
    pb01 = pk_fma(sb1,w1l,pb01); pb23 = pk_fma(sb1,w1h,pb23);
    pb01 = pk_fma(sb2,w2l,pb01); pb23 = pk_fma(sb2,w2h,pb23);
    pb01 = pk_fma(sb3,w3l,pb01); pb23 = pk_fma(sb3,w3h,pb23);
    accA01 = pk_add(accA01,pa01); accA23 = pk_add(accA23,pa23);
    accB01 = pk_add(accB01,pb01); accB23 = pk_add(accB23,pb23);
    ura[NRS3] = make_uint2(cvtpk_bf16(pa01.x,pa01.y), cvtpk_bf16(pa23.x,pa23.y));
    urb[NRS3] = make_uint2(cvtpk_bf16(pb01.x,pb01.y), cvtpk_bf16(pb23.x,pb23.y));
  }

  // u register prefetch for chunk 0
  float4 ua = *(const float4*)(Ub0 + (size_t)q * 4);
  float4 ub = *(const float4*)(Ub1 + (size_t)q * 4);

  #pragma unroll
  for (int c = 0; c < NCH; ++c){
    __syncthreads();                  // chunk c landed (DMA issued last iter)
    if (c + 1 < NCH) dma(c + 1, (c + 1) & 1);
    float4 cua = ua, cub = ub;
    if (c + 1 < NCH){                 // prefetch next chunk's u (independent)
      int rn = ((c + 1) << 7) + q;
      ua = *(const float4*)(Ub0 + (size_t)rn * 4);
      ub = *(const float4*)(Ub1 + (size_t)rn * 4);
    }
    // W from LDS stage: floats q*64 + qo*4 + j*16
    const float* wb = &wst[c & 1][(q << 6) + (qo << 2)];
    float4 w0 = *(const float4*)(wb);
    float4 w1 = *(const float4*)(wb + 16);
    float4 w2 = *(const float4*)(wb + 32);
    float4 w3 = *(const float4*)(wb + 48);
    v2f w0l={w0.x,w0.y}, w0h={w0.z,w0.w}, w1l={w1.x,w1.y}, w1h={w1.z,w1.w};
    v2f w2l={w2.x,w2.y}, w2h={w2.z,w2.w}, w3l={w3.x,w3.y}, w3h={w3.z,w3.w};
    v2f sa0={cua.x,cua.x}, sa1={cua.y,cua.y}, sa2={cua.z,cua.z}, sa3={cua.w,cua.w};
    v2f sb0={cub.x,cub.x}, sb1={cub.y,cub.y}, sb2={cub.z,cub.z}, sb3={cub.w,cub.w};
    v2f pa01 = pk_mul(sa0,w0l), pa23 = pk_mul(sa0,w0h);
    pa01 = pk_fma(sa1,w1l,pa01); pa23 = pk_fma(sa1,w1h,pa23);
    pa01 = pk_fma(sa2,w2l,pa01); pa23 = pk_fma(sa2,w2h,pa23);
    pa01 = pk_fma(sa3,w3l,pa01); pa23 = pk_fma(sa3,w3h,pa23);
    v2f pb01 = pk_mul(sb0,w0l), pb23 = pk_mul(sb0,w0h);
    pb01 = pk_fma(sb1,w1l,pb01); pb23 = pk_fma(sb1,w1h,pb23);
    pb01 = pk_fma(sb2,w2l,pb01); pb23 = pk_fma(sb2,w2h,pb23);
    pb01 = pk_fma(sb3,w3l,pb01); pb23 = pk_fma(sb3,w3h,pb23);
    accA01 = pk_add(accA01,pa01); accA23 = pk_add(accA23,pa23);
    accB01 = pk_add(accB01,pb01); accB23 = pk_add(accB23,pb23);
    int route = (c << 7) + q;
    if (c < 8){                       // compile-time split (full unroll)
      uj4[(route << 2) + qo] = make_uint4(
        cvtpk_bf16(pa01.x,pa01.y), cvtpk_bf16(pa23.x,pa23.y),
        cvtpk_bf16(pb01.x,pb01.y), cvtpk_bf16(pb23.x,pb23.y));
    } else {
      ura[c - 8] = make_uint2(cvtpk_bf16(pa01.x,pa01.y), cvtpk_bf16(pa23.x,pa23.y));
      urb[c - 8] = make_uint2(cvtpk_bf16(pb01.x,pb01.y), cvtpk_bf16(pb23.x,pb23.y));
    }
  }
  // per-lane route count: 18 chunks + tail (q<32 only)
  float l0 = (tid < 128) ? 19.f : 18.f;
  merge2(make_float4(accA01.x,accA01.y,accA23.x,accA23.y), l0,
         make_float4(accB01.x,accB01.y,accB23.x,accB23.y), l0,
         tid, red, vbuf, false, nullptr);                    // v0 (A,B)
  vA0 = vbuf[0][4*qo]; vA1 = vbuf[0][4*qo+1]; vA2 = vbuf[0][4*qo+2]; vA3 = vbuf[0][4*qo+3];
  vB0 = vbuf[1][4*qo]; vB1 = vbuf[1][4*qo+1]; vB2 = vbuf[1][4*qo+2]; vB3 = vbuf[1][4*qo+3];

  // ---------------- Passes 2,3 (pass 3 uses vc = v0+v1; b starts at 0) ----
  for (int ps = 0; ps < 2; ++ps){
    const float SH = ps ? SH2 : SH1;
    float4 accA = make_float4(0.f,0.f,0.f,0.f), accB = make_float4(0.f,0.f,0.f,0.f);
    float lpA = 0.f, lpB = 0.f;
    #pragma unroll
    for (int s = 0; s < NSL3; ++s){   // 8 exact slices: idx always < RL*4
      int idx = tid + (s << 9);
      uint4 q4 = uj4[idx];            // one ds_read_b128: both batches
      float a0 = blo(q4.x), a1 = bhi(q4.x), a2 = blo(q4.y), a3 = bhi(q4.y);
      float c0 = blo(q4.z), c1 = bhi(q4.z), c2 = blo(q4.w), c3 = bhi(q4.w);
      float dA = fmaf(a0, vA0, fmaf(a1, vA1, fmaf(a2, vA2, a3 * vA3)));
      float dB = fmaf(c0, vB0, fmaf(c1, vB1, fmaf(c2, vB2, c3 * vB3)));
      dA = qsum4(dA); dB = qsum4(dB);
      float eA = __expf(dA - SH), eB = __expf(dB - SH);
      lpA += eA; lpB += eB;
      accA.x = fmaf(eA, a0, accA.x); accA.y = fmaf(eA, a1, accA.y);
      accA.z = fmaf(eA, a2, accA.z); accA.w = fmaf(eA, a3, accA.w);
      accB.x = fmaf(eB, c0, accB.x); accB.y = fmaf(eB, c1, accB.y);
      accB.z = fmaf(eB, c2, accB.z); accB.w = fmaf(eB, c3, accB.w);
    }
    #pragma unroll
    for (int slot = 0; slot < NRS3; ++slot){  // residue slots 0..9 (all lanes)
      uint2 qa = ura[slot], qb = urb[slot];
      float a0 = blo(qa.x), a1 = bhi(qa.x), a2 = blo(qa.y), a3 = bhi(qa.y);
      float c0 = blo(qb.x), c1 = bhi(qb.x), c2 = blo(qb.y), c3 = bhi(qb.y);
      float dA = fmaf(a0, vA0, fmaf(a1, vA1, fmaf(a2, vA2, a3 * vA3)));
      float dB = fmaf(c0, vB0, fmaf(c1, vB1, fmaf(c2, vB2, c3 * vB3)));
      dA = qsum4(dA); dB = qsum4(dB);
      float eA = __expf(dA - SH), eB = __expf(dB - SH);
      lpA += eA; lpB += eB;
      accA.x = fmaf(eA, a0, accA.x); accA.y = fmaf(eA, a1, accA.y);
      accA.z = fmaf(eA, a2, accA.z); accA.w = fmaf(eA, a3, accA.w);
      accB.x = fmaf(eB, c0, accB.x); accB.y = fmaf(eB, c1, accB.y);
      accB.z = fmaf(eB, c2, accB.z); accB.w = fmaf(eB, c3, accB.w);
    }
    if (tid < 128){                   // tail slot 10: quads q<32 only
      uint2 qa = ura[NRS3], qb = urb[NRS3];
      float a0 = blo(qa.x), a1 = bhi(qa.x), a2 = blo(qa.y), a3 = bhi(qa.y);
      float c0 = blo(qb.x), c1 = bhi(qb.x), c2 = blo(qb.y), c3 = bhi(qb.y);
      float dA = fmaf(a0, vA0, fmaf(a1, vA1, fmaf(a2, vA2, a3 * vA3)));
      float dB = fmaf(c0, vB0, fmaf(c1, vB1, fmaf(c2, vB2, c3 * vB3)));
      dA = qsum4(dA); dB = qsum4(dB);
      float eA = __expf(dA - SH), eB = __expf(dB - SH);
      lpA += eA; lpB += eB;
      accA.x = fmaf(eA, a0, accA.x); accA.y = fmaf(eA, a1, accA.y);
      accA.z = fmaf(eA, a2, accA.z); accA.w = fmaf(eA, a3, accA.w);
      accB.x = fmaf(eB, c0, accB.x); accB.y = fmaf(eB, c1, accB.y);
      accB.z = fmaf(eB, c2, accB.z); accB.w = fmaf(eB, c3, accB.w);
    }
    merge2(accA, lpA, accB, lpB, tid, red, vbuf, ps == 1,
           Out + (bb << 1) + k);      // last: Out[bb*2+k], Out[(bb+1)*2+k]
    if (ps == 0){                     // b2 = uji.(v0+v1): accumulate v
      vA0 += vbuf[0][4*qo]; vA1 += vbuf[0][4*qo+1];
      vA2 += vbuf[0][4*qo+2]; vA3 += vbuf[0][4*qo+3];
      vB0 += vbuf[1][4*qo]; vB1 += vbuf[1][4*qo+1];
      vB2 += vbuf[1][4*qo+2]; vB3 += vbuf[1][4*qo+3];
    }
  }
}

// In-place 2-way softmax over k: Out[b,0..1] fp32
__global__ void caps_softmax(float* __restrict__ Out){
  int b = blockIdx.x * blockDim.x + threadIdx.x;
  if (b < BATCH){
    float2* p = (float2*)Out;
    float2 c = p[b];
    float m  = fmaxf(c.x, c.y);
    float e0 = __expf(c.x - m), e1 = __expf(c.y - m);
    float inv = 1.f / (e0 + e1);
    p[b] = make_float2(e0 * inv, e1 * inv);
  }
}

extern "C" void kernel_launch(void* const* d_in, const int* in_sizes, int n_in,
                              void* d_out, int out_size, void* d_ws, size_t ws_size,
                              hipStream_t stream) {
  const float* U = (const float*)d_in[0];   // [1024, 2336, 4] fp32
  const float* W = (const float*)d_in[1];   // [2, 2336, 4, 16] fp32
  float* Out = (float*)d_out;               // [1024, 2] fp32
  caps_route<<<dim3(NBLK), dim3(NTH), 0, stream>>>(U, W, Out);
  caps_softmax<<<dim3(BATCH / 256), dim3(256), 0, stream>>>(Out);
}

// Round 19
// 158.310 us; speedup vs baseline: 1.0202x; 1.0202x over previous
//
#include <hip/hip_runtime.h>
#include <stdint.h>

#define RT    2336          // routes
#define RL    1024          // uji routes in LDS per batch (chunks 0..7)
#define NCH   18            // DMA-staged W chunks of 128 routes (0..2303)
#define NRS3  10            // residue slots from chunks 8..17 (+1 tail slot)
#define NSL3  8             // pass slices over uji: RL*4/512 EXACT (no tail)
#define NTH   512
#define NBLK  1024          // one block per (b-pair, k), XCD swizzled
#define BATCH 1024
#define SH1   32.0f         // fixed softmax exponent shift, pass 2 (ratio cancels)
#define SH2   64.0f         // fixed softmax exponent shift, pass 3

typedef float v2f __attribute__((ext_vector_type(2)));

__device__ __forceinline__ float blo(uint32_t v){ union {uint32_t u; float f;} x; x.u = v << 16;        return x.f; }
__device__ __forceinline__ float bhi(uint32_t v){ union {uint32_t u; float f;} x; x.u = v & 0xffff0000u; return x.f; }

// 2x f32 -> packed bf16, one instruction (RNE; R13-verified bit-identical).
__device__ __forceinline__ uint32_t cvtpk_bf16(float a, float b){
  uint32_t r;
  asm("v_cvt_pk_bf16_f32 %0, %1, %2" : "=v"(r) : "v"(a), "v"(b));
  return r;
}

// Packed 2x f32 VOP3P: exact f32 math, half the issue count (R13-verified).
__device__ __forceinline__ v2f pk_fma(v2f a, v2f b, v2f c){
  v2f d; asm("v_pk_fma_f32 %0, %1, %2, %3" : "=v"(d) : "v"(a), "v"(b), "v"(c));
  return d;
}
__device__ __forceinline__ v2f pk_mul(v2f a, v2f b){
  v2f d; asm("v_pk_mul_f32 %0, %1, %2" : "=v"(d) : "v"(a), "v"(b));
  return d;
}
__device__ __forceinline__ v2f pk_add(v2f a, v2f b){
  v2f d; asm("v_pk_add_f32 %0, %1, %2" : "=v"(d) : "v"(a), "v"(b));
  return d;
}

// Quad (4-lane) all-reduce sum via DPP quad_perm (VALU pipe, no LDS).
__device__ __forceinline__ float qsum4(float d){
  d += __int_as_float(__builtin_amdgcn_update_dpp(
         0, __float_as_int(d), 0xB1, 0xF, 0xF, true));
  d += __int_as_float(__builtin_amdgcn_update_dpp(
         0, __float_as_int(d), 0x4E, 0xF, 0xF, true));
  return d;
}

// Dual-batch block merge: batches A,B reduced in one barrier pair.
__device__ __forceinline__ void merge2(float4 aA, float lA, float4 aB, float lB,
                                       int tid, float (*red)[8][4][5],
                                       float (*vbuf)[16],
                                       bool last, float* outp){
  #pragma unroll
  for (int off = 32; off >= 4; off >>= 1){
    aA.x += __shfl_down(aA.x, off); aA.y += __shfl_down(aA.y, off);
    aA.z += __shfl_down(aA.z, off); aA.w += __shfl_down(aA.w, off);
    lA   += __shfl_down(lA,   off);
    aB.x += __shfl_down(aB.x, off); aB.y += __shfl_down(aB.y, off);
    aB.z += __shfl_down(aB.z, off); aB.w += __shfl_down(aB.w, off);
    lB   += __shfl_down(lB,   off);
  }
  const int lane = tid & 63, wid = tid >> 6;
  if (lane < 4){
    red[0][wid][lane][0] = lA;
    red[0][wid][lane][1] = aA.x; red[0][wid][lane][2] = aA.y;
    red[0][wid][lane][3] = aA.z; red[0][wid][lane][4] = aA.w;
    red[1][wid][lane][0] = lB;
    red[1][wid][lane][1] = aB.x; red[1][wid][lane][2] = aB.y;
    red[1][wid][lane][3] = aB.z; red[1][wid][lane][4] = aB.w;
  }
  __syncthreads();
  if (tid < 32){
    const int bt = tid >> 4, t = tid & 15, q = t >> 2, j = t & 3;
    float S = 0.f, partL = 0.f;
    #pragma unroll
    for (int w = 0; w < 8; ++w){
      S     += red[bt][w][q][1 + j];
      partL += red[bt][w][j][0];
    }
    partL += __shfl_xor(partL, 1);
    partL += __shfl_xor(partL, 2);
    float L   = partL * 0.25f;        // 4 qo-threads count each route once
    float inv = 1.f / L;
    float Sn  = S * inv;              // s = acc / L
    float nrm = Sn * Sn;              // squared norm over 16 outputs
    nrm += __shfl_xor(nrm, 1);
    nrm += __shfl_xor(nrm, 2);
    nrm += __shfl_xor(nrm, 4);
    nrm += __shfl_xor(nrm, 8);
    if (last){
      if (t == 0) outp[bt << 1] = nrm / (1.f + nrm);  // ||squash|| = n/(1+n)
    } else {
      float f = sqrtf(nrm) / (1.f + nrm);
      vbuf[bt][t] = Sn * f;
    }
  }
  __syncthreads();
}

// R18 post-mortem BISECT: R17's bundle (swizzle + barrier-free counted-vmcnt)
// FAILED verify at 1.95e-2 (~5 bf16 ulp) — small error, consistent with
// occasional stale ds_reads racing the DMA's LDS-write commit. The swizzle
// algebra is verified (3 concrete address triples); every guide-verified
// global_load_lds pattern has vmcnt + S_BARRIER before ds_read. So: KEEP the
// swizzle (kills the measured 7.13M bank-conflict cycles), RESTORE R16's
// __syncthreads-per-chunk (the known-correct ordering; barrier drain =
// vmcnt(0) before s_barrier). If this passes: sync discipline was the bug.
__global__ void __launch_bounds__(NTH, 1)
caps_route(const float* __restrict__ U, const float* __restrict__ W,
           float* __restrict__ Out){
  __shared__ uint4 uj4[RL * 4];       // 64 KiB  [route*4+qo] {A01,A23,B01,B23}
  __shared__ float wst[2][8192];      // 2 x 32 KiB W stage (swizzled f32)
  __shared__ float red[2][8][4][5];   // 1.25 KiB
  __shared__ float vbuf[2][16];

  const int tid  = threadIdx.x;
  const int qo   = tid & 3;           // my o-quad: o = 4*qo .. 4*qo+3
  const int q    = tid >> 2;          // quad id = route index within a chunk
  const int wv   = tid >> 6;          // wave id (wave-uniform)
  const int lane = tid & 63;

  // XCD swizzle (bijective): k=0/1 of one pair adjacent on same XCD.
  const int c8   = blockIdx.x & 7;
  const int jj   = blockIdx.x >> 3;   // 0..127
  const int k    = jj & 1;
  const int pair = (c8 << 6) | (jj >> 1);  // 0..511
  const int bb   = pair << 1;         // b0 = bb, b1 = bb+1

  const float* Ub0 = U + (size_t)bb * (RT * 4);
  const float* Ub1 = Ub0 + (RT * 4);
  const char*  Wb  = (const char*)W + (size_t)k * RT * 256;  // W_k, 256 B/route

  uint2 ura[NRS3 + 1], urb[NRS3 + 1]; // bf16-packed residue (+ tail slot 10)
  float vA0,vA1,vA2,vA3, vB0,vB1,vB2,vB3;

  // Async DMA one 32 KiB W chunk -> wst[buf], PRE-SWIZZLED global source:
  // HW writes lane i at phys x = wv*4096 + j*1024 + i*16; we fetch from
  // logical y = x ^ (((x>>8)&7)<<4); key = (j&1)*4 + (lane>>4).
  auto dma = [&](int c, int buf){
    #pragma unroll
    for (int j = 0; j < 4; ++j){
      int key = ((j & 1) << 2) | (lane >> 4);
      const char* g = Wb + ((size_t)c << 15) + (wv << 12) + (j << 10)
                      + ((lane << 4) ^ (key << 4));
      char* l = (char*)&wst[buf][0] + (wv << 12) + (j << 10);
      __builtin_amdgcn_global_load_lds(
        (const __attribute__((address_space(1))) uint32_t*)g,
        (__attribute__((address_space(3))) uint32_t*)l, 16, 0, 0);
    }
  };

  v2f accA01={0.f,0.f}, accA23={0.f,0.f}, accB01={0.f,0.f}, accB23={0.f,0.f};

  // ---------------- Phase A -------------------------------------------------
  dma(0, 0);                          // chunk 0 in flight

  // Tail routes 2304..2335 (quads q<32): direct from global; overlaps DMA 0.
  if (tid < 128){
    int rt = 2304 + q;
    float4 ua = *(const float4*)(Ub0 + (size_t)rt * 4);
    float4 ub = *(const float4*)(Ub1 + (size_t)rt * 4);
    const float* wr = (const float*)(Wb + (size_t)rt * 256) + (qo << 2);
    float4 w0 = *(const float4*)(wr);
    float4 w1 = *(const float4*)(wr + 16);
    float4 w2 = *(const float4*)(wr + 32);
    float4 w3 = *(const float4*)(wr + 48);
    v2f w0l={w0.x,w0.y}, w0h={w0.z,w0.w}, w1l={w1.x,w1.y}, w1h={w1.z,w1.w};
    v2f w2l={w2.x,w2.y}, w2h={w2.z,w2.w}, w3l={w3.x,w3.y}, w3h={w3.z,w3.w};
    v2f sa0={ua.x,ua.x}, sa1={ua.y,ua.y}, sa2={ua.z,ua.z}, sa3={ua.w,ua.w};
    v2f sb0={ub.x,ub.x}, sb1={ub.y,ub.y}, sb2={ub.z,ub.z}, sb3={ub.w,ub.w};
    v2f pa01 = pk_mul(sa0,w0l), pa23 = pk_mul(sa0,w0h);
    pa01 = pk_fma(sa1,w1l,pa01); pa23 = pk_fma(sa1,w1h,pa23);
    pa01 = pk_fma(sa2,w2l,pa01); pa23 = pk_fma(sa2,w2h,pa23);
    pa01 = pk_fma(sa3,w3l,pa01); pa23 = pk_fma(sa3,w3h,pa23);
    v2f pb01 = pk_mul(sb0,w0l), pb23 = pk_mul(sb0,w0h);
    pb01 = pk_fma(sb1,w1l,pb01); pb23 = pk_fma(sb1,w1h,pb23);
    pb01 = pk_fma(sb2,w2l,pb01); pb23 = pk_fma(sb2,w2h,pb23);
    pb01 = pk_fma(sb3,w3l,pb01); pb23 = pk_fma(sb3,w3h,pb23);
    accA01 = pk_add(accA01,pa01); accA23 = pk_add(accA23,pa23);
    accB01 = pk_add(accB01,pb01); accB23 = pk_add(accB23,pb23);
    ura[NRS3] = make_uint2(cvtpk_bf16(pa01.x,pa01.y), cvtpk_bf16(pa23.x,pa23.y));
    urb[NRS3] = make_uint2(cvtpk_bf16(pb01.x,pb01.y), cvtpk_bf16(pb23.x,pb23.y));
  }

  // u register prefetch for chunk 0
  float4 ua = *(const float4*)(Ub0 + (size_t)q * 4);
  float4 ub = *(const float4*)(Ub1 + (size_t)q * 4);

  const int sw = (q & 7) << 4;        // read-side swizzle key for my route row

  #pragma unroll
  for (int c = 0; c < NCH; ++c){
    __syncthreads();                  // drains dma(c): vmcnt(0) before barrier
    if (c + 1 < NCH) dma(c + 1, (c + 1) & 1);
    float4 cua = ua, cub = ub;
    if (c + 1 < NCH){                 // prefetch next chunk's u (independent)
      int rn = ((c + 1) << 7) + q;
      ua = *(const float4*)(Ub0 + (size_t)rn * 4);
      ub = *(const float4*)(Ub1 + (size_t)rn * 4);
    }
    // W from own wave's LDS segment, swizzled offsets (uniform 8-lane slots)
    const char* wrow = (const char*)&wst[c & 1][0] + (q << 8);
    float4 w0 = *(const float4*)(wrow + (((qo << 4)      ) ^ sw));
    float4 w1 = *(const float4*)(wrow + (((qo << 4) +  64) ^ sw));
    float4 w2 = *(const float4*)(wrow + (((qo << 4) + 128) ^ sw));
    float4 w3 = *(const float4*)(wrow + (((qo << 4) + 192) ^ sw));
    v2f w0l={w0.x,w0.y}, w0h={w0.z,w0.w}, w1l={w1.x,w1.y}, w1h={w1.z,w1.w};
    v2f w2l={w2.x,w2.y}, w2h={w2.z,w2.w}, w3l={w3.x,w3.y}, w3h={w3.z,w3.w};
    v2f sa0={cua.x,cua.x}, sa1={cua.y,cua.y}, sa2={cua.z,cua.z}, sa3={cua.w,cua.w};
    v2f sb0={cub.x,cub.x}, sb1={cub.y,cub.y}, sb2={cub.z,cub.z}, sb3={cub.w,cub.w};
    v2f pa01 = pk_mul(sa0,w0l), pa23 = pk_mul(sa0,w0h);
    pa01 = pk_fma(sa1,w1l,pa01); pa23 = pk_fma(sa1,w1h,pa23);
    pa01 = pk_fma(sa2,w2l,pa01); pa23 = pk_fma(sa2,w2h,pa23);
    pa01 = pk_fma(sa3,w3l,pa01); pa23 = pk_fma(sa3,w3h,pa23);
    v2f pb01 = pk_mul(sb0,w0l), pb23 = pk_mul(sb0,w0h);
    pb01 = pk_fma(sb1,w1l,pb01); pb23 = pk_fma(sb1,w1h,pb23);
    pb01 = pk_fma(sb2,w2l,pb01); pb23 = pk_fma(sb2,w2h,pb23);
    pb01 = pk_fma(sb3,w3l,pb01); pb23 = pk_fma(sb3,w3h,pb23);
    accA01 = pk_add(accA01,pa01); accA23 = pk_add(accA23,pa23);
    accB01 = pk_add(accB01,pb01); accB23 = pk_add(accB23,pb23);
    int route = (c << 7) + q;
    if (c < 8){                       // compile-time split (full unroll)
      uj4[(route << 2) + qo] = make_uint4(
        cvtpk_bf16(pa01.x,pa01.y), cvtpk_bf16(pa23.x,pa23.y),
        cvtpk_bf16(pb01.x,pb01.y), cvtpk_bf16(pb23.x,pb23.y));
    } else {
      ura[c - 8] = make_uint2(cvtpk_bf16(pa01.x,pa01.y), cvtpk_bf16(pa23.x,pa23.y));
      urb[c - 8] = make_uint2(cvtpk_bf16(pb01.x,pb01.y), cvtpk_bf16(pb23.x,pb23.y));
    }
  }
  // per-lane route count: 18 chunks + tail (q<32 only)
  float l0 = (tid < 128) ? 19.f : 18.f;
  merge2(make_float4(accA01.x,accA01.y,accA23.x,accA23.y), l0,
         make_float4(accB01.x,accB01.y,accB23.x,accB23.y), l0,
         tid, red, vbuf, false, nullptr);                    // v0 (A,B)
  vA0 = vbuf[0][4*qo]; vA1 = vbuf[0][4*qo+1]; vA2 = vbuf[0][4*qo+2]; vA3 = vbuf[0][4*qo+3];
  vB0 = vbuf[1][4*qo]; vB1 = vbuf[1][4*qo+1]; vB2 = vbuf[1][4*qo+2]; vB3 = vbuf[1][4*qo+3];

  // ---------------- Passes 2,3 (pass 3 uses vc = v0+v1; b starts at 0) ----
  for (int ps = 0; ps < 2; ++ps){
    const float SH = ps ? SH2 : SH1;
    float4 accA = make_float4(0.f,0.f,0.f,0.f), accB = make_float4(0.f,0.f,0.f,0.f);
    float lpA = 0.f, lpB = 0.f;
    #pragma unroll
    for (int s = 0; s < NSL3; ++s){   // 8 exact slices: idx always < RL*4
      int idx = tid + (s << 9);
      uint4 q4 = uj4[idx];            // one ds_read_b128: both batches
      float a0 = blo(q4.x), a1 = bhi(q4.x), a2 = blo(q4.y), a3 = bhi(q4.y);
      float c0 = blo(q4.z), c1 = bhi(q4.z), c2 = blo(q4.w), c3 = bhi(q4.w);
      float dA = fmaf(a0, vA0, fmaf(a1, vA1, fmaf(a2, vA2, a3 * vA3)));
      float dB = fmaf(c0, vB0, fmaf(c1, vB1, fmaf(c2, vB2, c3 * vB3)));
      dA = qsum4(dA); dB = qsum4(dB);
      float eA = __expf(dA - SH), eB = __expf(dB - SH);
      lpA += eA; lpB += eB;
      accA.x = fmaf(eA, a0, accA.x); accA.y = fmaf(eA, a1, accA.y);
      accA.z = fmaf(eA, a2, accA.z); accA.w = fmaf(eA, a3, accA.w);
      accB.x = fmaf(eB, c0, accB.x); accB.y = fmaf(eB, c1, accB.y);
      accB.z = fmaf(eB, c2, accB.z); accB.w = fmaf(eB, c3, accB.w);
    }
    #pragma unroll
    for (int slot = 0; slot < NRS3; ++slot){  // residue slots 0..9 (all lanes)
      uint2 qa = ura[slot], qb = urb[slot];
      float a0 = blo(qa.x), a1 = bhi(qa.x), a2 = blo(qa.y), a3 = bhi(qa.y);
      float c0 = blo(qb.x), c1 = bhi(qb.x), c2 = blo(qb.y), c3 = bhi(qb.y);
      float dA = fmaf(a0, vA0, fmaf(a1, vA1, fmaf(a2, vA2, a3 * vA3)));
      float dB = fmaf(c0, vB0, fmaf(c1, vB1, fmaf(c2, vB2, c3 * vB3)));
      dA = qsum4(dA); dB = qsum4(dB);
      float eA = __expf(dA - SH), eB = __expf(dB - SH);
      lpA += eA; lpB += eB;
      accA.x = fmaf(eA, a0, accA.x); accA.y = fmaf(eA, a1, accA.y);
      accA.z = fmaf(eA, a2, accA.z); accA.w = fmaf(eA, a3, accA.w);
      accB.x = fmaf(eB, c0, accB.x); accB.y = fmaf(eB, c1, accB.y);
      accB.z = fmaf(eB, c2, accB.z); accB.w = fmaf(eB, c3, accB.w);
    }
    if (tid < 128){                   // tail slot 10: quads q<32 only
      uint2 qa = ura[NRS3], qb = urb[NRS3];
      float a0 = blo(qa.x), a1 = bhi(qa.x), a2 = blo(qa.y), a3 = bhi(qa.y);
      float c0 = blo(qb.x), c1 = bhi(qb.x), c2 = blo(qb.y), c3 = bhi(qb.y);
      float dA = fmaf(a0, vA0, fmaf(a1, vA1, fmaf(a2, vA2, a3 * vA3)));
      float dB = fmaf(c0, vB0, fmaf(c1, vB1, fmaf(c2, vB2, c3 * vB3)));
      dA = qsum4(dA); dB = qsum4(dB);
      float eA = __expf(dA - SH), eB = __expf(dB - SH);
      lpA += eA; lpB += eB;
      accA.x = fmaf(eA, a0, accA.x); accA.y = fmaf(eA, a1, accA.y);
      accA.z = fmaf(eA, a2, accA.z); accA.w = fmaf(eA, a3, accA.w);
      accB.x = fmaf(eB, c0, accB.x); accB.y = fmaf(eB, c1, accB.y);
      accB.z = fmaf(eB, c2, accB.z); accB.w = fmaf(eB, c3, accB.w);
    }
    merge2(accA, lpA, accB, lpB, tid, red, vbuf, ps == 1,
           Out + (bb << 1) + k);      // last: Out[bb*2+k], Out[(bb+1)*2+k]
    if (ps == 0){                     // b2 = uji.(v0+v1): accumulate v
      vA0 += vbuf[0][4*qo]; vA1 += vbuf[0][4*qo+1];
      vA2 += vbuf[0][4*qo+2]; vA3 += vbuf[0][4*qo+3];
      vB0 += vbuf[1][4*qo]; vB1 += vbuf[1][4*qo+1];
      vB2 += vbuf[1][4*qo+2]; vB3 += vbuf[1][4*qo+3];
    }
  }
}

// In-place 2-way softmax over k: Out[b,0..1] fp32
__global__ void caps_softmax(float* __restrict__ Out){
  int b = blockIdx.x * blockDim.x + threadIdx.x;
  if (b < BATCH){
    float2* p = (float2*)Out;
    float2 c = p[b];
    float m  = fmaxf(c.x, c.y);
    float e0 = __expf(c.x - m), e1 = __expf(c.y - m);
    float inv = 1.f / (e0 + e1);
    p[b] = make_float2(e0 * inv, e1 * inv);
  }
}

extern "C" void kernel_launch(void* const* d_in, const int* in_sizes, int n_in,
                              void* d_out, int out_size, void* d_ws, size_t ws_size,
                              hipStream_t stream) {
  const float* U = (const float*)d_in[0];   // [1024, 2336, 4] fp32
  const float* W = (const float*)d_in[1];   // [2, 2336, 4, 16] fp32
  float* Out = (float*)d_out;               // [1024, 2] fp32
  caps_route<<<dim3(NBLK), dim3(NTH), 0, stream>>>(U, W, Out);
  caps_softmax<<<dim3(BATCH / 256), dim3(256), 0, stream>>>(Out);
}

// Round 21
// 132.798 us; speedup vs baseline: 1.2162x; 1.1921x over previous
//
#include <hip/hip_runtime.h>
#include <stdint.h>

#define RT    2336          // routes
#define RL    928           // LDS-resident routes per batch (32 + 7*128)
#define NSL2  8             // pass slices: ceil(RL*4/512); slice 7 covers 128
#define NRS2  11            // bf16 register residue slots: (RT-RL)/128 = 11
#define NTH   512
#define NBLK  1024          // one block per (b-pair, k), XCD swizzled
#define BATCH 1024
#define SH1   32.0f         // fixed softmax exponent shift, pass 2 (ratio cancels)
#define SH2   64.0f         // fixed softmax exponent shift, pass 3

typedef float v2f __attribute__((ext_vector_type(2)));

__device__ __forceinline__ float blo(uint32_t v){ union {uint32_t u; float f;} x; x.u = v << 16;        return x.f; }
__device__ __forceinline__ float bhi(uint32_t v){ union {uint32_t u; float f;} x; x.u = v & 0xffff0000u; return x.f; }

// 2x f32 -> packed bf16, ONE instruction (RNE on gfx950; R13-verified
// bit-identical to the manual ~10-op pack).
__device__ __forceinline__ uint32_t cvtpk_bf16(float a, float b){
  uint32_t r;
  asm("v_cvt_pk_bf16_f32 %0, %1, %2" : "=v"(r) : "v"(a), "v"(b));
  return r;
}

// Packed 2x f32 VOP3P ops: exact f32 math, half the issue count.
__device__ __forceinline__ v2f pk_fma(v2f a, v2f b, v2f c){
  v2f d; asm("v_pk_fma_f32 %0, %1, %2, %3" : "=v"(d) : "v"(a), "v"(b), "v"(c));
  return d;
}
__device__ __forceinline__ v2f pk_mul(v2f a, v2f b){
  v2f d; asm("v_pk_mul_f32 %0, %1, %2" : "=v"(d) : "v"(a), "v"(b));
  return d;
}
__device__ __forceinline__ v2f pk_add(v2f a, v2f b){
  v2f d; asm("v_pk_add_f32 %0, %1, %2" : "=v"(d) : "v"(a), "v"(b));
  return d;
}

// Quad (4-lane) all-reduce sum via DPP quad_perm (VALU pipe, no LDS).
__device__ __forceinline__ float qsum4(float d){
  d += __int_as_float(__builtin_amdgcn_update_dpp(
         0, __float_as_int(d), 0xB1, 0xF, 0xF, true));
  d += __int_as_float(__builtin_amdgcn_update_dpp(
         0, __float_as_int(d), 0x4E, 0xF, 0xF, true));
  return d;
}

// Dual-batch block merge: batches A,B reduced in one barrier pair.
__device__ __forceinline__ void merge2(float4 aA, float lA, float4 aB, float lB,
                                       int tid, float (*red)[8][4][5],
                                       float (*vbuf)[16],
                                       bool last, float* outp){
  #pragma unroll
  for (int off = 32; off >= 4; off >>= 1){
    aA.x += __shfl_down(aA.x, off); aA.y += __shfl_down(aA.y, off);
    aA.z += __shfl_down(aA.z, off); aA.w += __shfl_down(aA.w, off);
    lA   += __shfl_down(lA,   off);
    aB.x += __shfl_down(aB.x, off); aB.y += __shfl_down(aB.y, off);
    aB.z += __shfl_down(aB.z, off); aB.w += __shfl_down(aB.w, off);
    lB   += __shfl_down(lB,   off);
  }
  const int lane = tid & 63, wid = tid >> 6;
  if (lane < 4){
    red[0][wid][lane][0] = lA;
    red[0][wid][lane][1] = aA.x; red[0][wid][lane][2] = aA.y;
    red[0][wid][lane][3] = aA.z; red[0][wid][lane][4] = aA.w;
    red[1][wid][lane][0] = lB;
    red[1][wid][lane][1] = aB.x; red[1][wid][lane][2] = aB.y;
    red[1][wid][lane][3] = aB.z; red[1][wid][lane][4] = aB.w;
  }
  __syncthreads();
  if (tid < 32){
    const int bt = tid >> 4, t = tid & 15, q = t >> 2, j = t & 3;
    float S = 0.f, partL = 0.f;
    #pragma unroll
    for (int w = 0; w < 8; ++w){
      S     += red[bt][w][q][1 + j];
      partL += red[bt][w][j][0];
    }
    partL += __shfl_xor(partL, 1);
    partL += __shfl_xor(partL, 2);
    float L   = partL * 0.25f;        // 4 qo-threads count each route once
    float inv = 1.f / L;
    float Sn  = S * inv;              // s = acc / L
    float nrm = Sn * Sn;              // squared norm over 16 outputs
    nrm += __shfl_xor(nrm, 1);
    nrm += __shfl_xor(nrm, 2);
    nrm += __shfl_xor(nrm, 4);
    nrm += __shfl_xor(nrm, 8);
    if (last){
      if (t == 0) outp[bt << 1] = nrm / (1.f + nrm);  // ||squash|| = n/(1+n)
    } else {
      float f = sqrtf(nrm) / (1.f + nrm);
      vbuf[bt][t] = Sn * f;
    }
  }
  __syncthreads();
}

// R13 config — session best (bench 133.5 us, dispatch ~78 us). Batch-pair
// block: W loads shared across 2 batches (halves L2 W-traffic), dual
// independent FMA/exp chains (ILP covers the VGPR>64 occupancy penalty).
// Instruction diet: cvt_pk bf16 pack (1 op vs ~10), pk_fma/pk_mul/pk_add
// packed f32, uint4 LDS (1 ds_read_b128 for both batches), compile-time
// route counts. DMA-staged W (R15-R19) measured SLOWER (108 us): required
// per-chunk barriers at 1 block/CU beat the gain; direct loads + compiler
// scheduling win. launch_bounds arg=2 -> VGPR cap 128; compiles to 100.
__global__ void __launch_bounds__(NTH, 2)
caps_route(const float* __restrict__ U, const float* __restrict__ W,
           float* __restrict__ Out){
  __shared__ uint4 uj4[RL * 4];       // [route*4 + qo] : {A01,A23,B01,B23}
  __shared__ float red[2][8][4][5];
  __shared__ float vbuf[2][16];

  const int tid = threadIdx.x;
  const int qo  = tid & 3;            // my o-quad: o = 4*qo .. 4*qo+3

  // XCD swizzle (bijective): k=0/1 of one pair adjacent on same XCD.
  const int c    = blockIdx.x & 7;
  const int jj   = blockIdx.x >> 3;   // 0..127
  const int k    = jj & 1;
  const int pair = (c << 6) | (jj >> 1);   // 0..511
  const int bb   = pair << 1;         // b0 = bb, b1 = bb+1

  const float* Ub0 = U + (size_t)bb * (RT * 4);
  const float* Ub1 = Ub0 + (RT * 4);
  const float* Wk  = W + (size_t)k * ((size_t)RT * 64) + qo * 4;

  uint2  ura[NRS2], urb[NRS2];        // bf16-packed residue
  float  vA0, vA1, vA2, vA3, vB0, vB1, vB2, vB3;

  // uji quads for both batches of route r; W row loaded once; packed f32 FMA.
  auto build2 = [&](int route, v2f& pa01, v2f& pa23, v2f& pb01, v2f& pb23){
    float4 ua = *(const float4*)(Ub0 + (size_t)route * 4);
    float4 ub = *(const float4*)(Ub1 + (size_t)route * 4);
    const float* wr = Wk + (size_t)route * 64;
    float4 w0 = *(const float4*)(wr);
    float4 w1 = *(const float4*)(wr + 16);
    float4 w2 = *(const float4*)(wr + 32);
    float4 w3 = *(const float4*)(wr + 48);
    v2f w0l = {w0.x,w0.y}, w0h = {w0.z,w0.w};
    v2f w1l = {w1.x,w1.y}, w1h = {w1.z,w1.w};
    v2f w2l = {w2.x,w2.y}, w2h = {w2.z,w2.w};
    v2f w3l = {w3.x,w3.y}, w3h = {w3.z,w3.w};
    v2f sa0 = {ua.x,ua.x}, sa1 = {ua.y,ua.y}, sa2 = {ua.z,ua.z}, sa3 = {ua.w,ua.w};
    v2f sb0 = {ub.x,ub.x}, sb1 = {ub.y,ub.y}, sb2 = {ub.z,ub.z}, sb3 = {ub.w,ub.w};
    pa01 = pk_mul(sa0, w0l);          pa23 = pk_mul(sa0, w0h);
    pa01 = pk_fma(sa1, w1l, pa01);    pa23 = pk_fma(sa1, w1h, pa23);
    pa01 = pk_fma(sa2, w2l, pa01);    pa23 = pk_fma(sa2, w2h, pa23);
    pa01 = pk_fma(sa3, w3l, pa01);    pa23 = pk_fma(sa3, w3h, pa23);
    pb01 = pk_mul(sb0, w0l);          pb23 = pk_mul(sb0, w0h);
    pb01 = pk_fma(sb1, w1l, pb01);    pb23 = pk_fma(sb1, w1h, pb23);
    pb01 = pk_fma(sb2, w2l, pb01);    pb23 = pk_fma(sb2, w2h, pb23);
    pb01 = pk_fma(sb3, w3l, pb01);    pb23 = pk_fma(sb3, w3h, pb23);
  };

  // ---------------- Phase A: build u_ji both batches; fused pass 1 --------
  v2f accA01 = {0.f,0.f}, accA23 = {0.f,0.f};
  v2f accB01 = {0.f,0.f}, accB23 = {0.f,0.f};

  if (tid < 128){                     // pre-step: routes 0..31
    int route = tid >> 2;
    v2f pa01, pa23, pb01, pb23;
    build2(route, pa01, pa23, pb01, pb23);
    accA01 = pk_add(accA01, pa01); accA23 = pk_add(accA23, pa23);
    accB01 = pk_add(accB01, pb01); accB23 = pk_add(accB23, pb23);
    uj4[route*4 + qo] = make_uint4(
      cvtpk_bf16(pa01.x, pa01.y), cvtpk_bf16(pa23.x, pa23.y),
      cvtpk_bf16(pb01.x, pb01.y), cvtpk_bf16(pb23.x, pb23.y));
  }
  #pragma unroll 3
  for (int s = 0; s < 7; ++s){        // LDS routes 32..927
    int route = 32 + s*128 + (tid >> 2);
    v2f pa01, pa23, pb01, pb23;
    build2(route, pa01, pa23, pb01, pb23);
    accA01 = pk_add(accA01, pa01); accA23 = pk_add(accA23, pa23);
    accB01 = pk_add(accB01, pb01); accB23 = pk_add(accB23, pb23);
    uj4[route*4 + qo] = make_uint4(
      cvtpk_bf16(pa01.x, pa01.y), cvtpk_bf16(pa23.x, pa23.y),
      cvtpk_bf16(pb01.x, pb01.y), cvtpk_bf16(pb23.x, pb23.y));
  }
  #pragma unroll
  for (int slot = 0; slot < NRS2; ++slot){  // reg routes 928..2335, static
    int route = RL + slot*128 + (tid >> 2);
    v2f pa01, pa23, pb01, pb23;
    build2(route, pa01, pa23, pb01, pb23);
    accA01 = pk_add(accA01, pa01); accA23 = pk_add(accA23, pa23);
    accB01 = pk_add(accB01, pb01); accB23 = pk_add(accB23, pb23);
    ura[slot] = make_uint2(cvtpk_bf16(pa01.x, pa01.y), cvtpk_bf16(pa23.x, pa23.y));
    urb[slot] = make_uint2(cvtpk_bf16(pb01.x, pb01.y), cvtpk_bf16(pb23.x, pb23.y));
  }
  // route counts are compile-time (pre-step threads handle one extra route)
  float lA = (tid < 128) ? 19.f : 18.f, lB = lA;
  merge2(make_float4(accA01.x, accA01.y, accA23.x, accA23.y), lA,
         make_float4(accB01.x, accB01.y, accB23.x, accB23.y), lB,
         tid, red, vbuf, false, nullptr);                     // v0 (A,B)
  vA0 = vbuf[0][4*qo]; vA1 = vbuf[0][4*qo+1]; vA2 = vbuf[0][4*qo+2]; vA3 = vbuf[0][4*qo+3];
  vB0 = vbuf[1][4*qo]; vB1 = vbuf[1][4*qo+1]; vB2 = vbuf[1][4*qo+2]; vB3 = vbuf[1][4*qo+3];

  // ---------------- Passes 2,3 (pass 3 uses vc = v0+v1; b starts at 0) ----
  for (int ps = 0; ps < 2; ++ps){
    const float SH = ps ? SH2 : SH1;
    float4 accA = make_float4(0.f,0.f,0.f,0.f), accB = make_float4(0.f,0.f,0.f,0.f);
    float lpA = 0.f, lpB = 0.f;
    #pragma unroll
    for (int s = 0; s < NSL2; ++s){   // LDS slices, idx = tid + 512*s
      int idx = tid + (s << 9);
      bool act = (idx < RL * 4);      // only s==7 partial (tid<128)
      float a0=0.f,a1=0.f,a2=0.f,a3=0.f, c0=0.f,c1=0.f,c2=0.f,c3=0.f;
      float dA = 0.f, dB = 0.f;
      if (act){
        uint4 q4 = uj4[idx];          // one ds_read_b128: both batches
        a0 = blo(q4.x); a1 = bhi(q4.x); a2 = blo(q4.y); a3 = bhi(q4.y);
        c0 = blo(q4.z); c1 = bhi(q4.z); c2 = blo(q4.w); c3 = bhi(q4.w);
        dA = fmaf(a0, vA0, fmaf(a1, vA1, fmaf(a2, vA2, a3 * vA3)));
        dB = fmaf(c0, vB0, fmaf(c1, vB1, fmaf(c2, vB2, c3 * vB3)));
      }
      dA = qsum4(dA); dB = qsum4(dB);
      if (act){
        float eA = __expf(dA - SH), eB = __expf(dB - SH);
        lpA += eA; lpB += eB;
        accA.x = fmaf(eA, a0, accA.x); accA.y = fmaf(eA, a1, accA.y);
        accA.z = fmaf(eA, a2, accA.z); accA.w = fmaf(eA, a3, accA.w);
        accB.x = fmaf(eB, c0, accB.x); accB.y = fmaf(eB, c1, accB.y);
        accB.z = fmaf(eB, c2, accB.z); accB.w = fmaf(eB, c3, accB.w);
      }
    }
    #pragma unroll
    for (int slot = 0; slot < NRS2; ++slot){  // residue slices (all active)
      uint2 qa = ura[slot], qb = urb[slot];
      float a0 = blo(qa.x), a1 = bhi(qa.x), a2 = blo(qa.y), a3 = bhi(qa.y);
      float c0 = blo(qb.x), c1 = bhi(qb.x), c2 = blo(qb.y), c3 = bhi(qb.y);
      float dA = fmaf(a0, vA0, fmaf(a1, vA1, fmaf(a2, vA2, a3 * vA3)));
      float dB = fmaf(c0, vB0, fmaf(c1, vB1, fmaf(c2, vB2, c3 * vB3)));
      dA = qsum4(dA); dB = qsum4(dB);
      float eA = __expf(dA - SH), eB = __expf(dB - SH);
      lpA += eA; lpB += eB;
      accA.x = fmaf(eA, a0, accA.x); accA.y = fmaf(eA, a1, accA.y);
      accA.z = fmaf(eA, a2, accA.z); accA.w = fmaf(eA, a3, accA.w);
      accB.x = fmaf(eB, c0, accB.x); accB.y = fmaf(eB, c1, accB.y);
      accB.z = fmaf(eB, c2, accB.z); accB.w = fmaf(eB, c3, accB.w);
    }
    merge2(accA, lpA, accB, lpB, tid, red, vbuf, ps == 1,
           Out + (bb << 1) + k);      // last: Out[bb*2+k], Out[(bb+1)*2+k]
    if (ps == 0){                     // b2 = uji.(v0+v1): accumulate v
      vA0 += vbuf[0][4*qo]; vA1 += vbuf[0][4*qo+1];
      vA2 += vbuf[0][4*qo+2]; vA3 += vbuf[0][4*qo+3];
      vB0 += vbuf[1][4*qo]; vB1 += vbuf[1][4*qo+1];
      vB2 += vbuf[1][4*qo+2]; vB3 += vbuf[1][4*qo+3];
    }
  }
}

// In-place 2-way softmax over k: Out[b,0..1] fp32
__global__ void caps_softmax(float* __restrict__ Out){
  int b = blockIdx.x * blockDim.x + threadIdx.x;
  if (b < BATCH){
    float2* p = (float2*)Out;
    float2 c = p[b];
    float m  = fmaxf(c.x, c.y);
    float e0 = __expf(c.x - m), e1 = __expf(c.y - m);
    float inv = 1.f / (e0 + e1);
    p[b] = make_float2(e0 * inv, e1 * inv);
  }
}

extern "C" void kernel_launch(void* const* d_in, const int* in_sizes, int n_in,
                              void* d_out, int out_size, void* d_ws, size_t ws_size,
                              hipStream_t stream) {
  const float* U = (const float*)d_in[0];   // [1024, 2336, 4] fp32
  const float* W = (const float*)d_in[1];   // [2, 2336, 4, 16] fp32
  float* Out = (float*)d_out;               // [1024, 2] fp32
  caps_route<<<dim3(NBLK), dim3(NTH), 0, stream>>>(U, W, Out);
  caps_softmax<<<dim3(BATCH / 256), dim3(256), 0, stream>>>(Out);
}